// Round 3
// baseline (292.495 us; speedup 1.0000x reference)
//
#include <hip/hip_runtime.h>
#include <math.h>

// FourierConv2D: B=16,H=W=128,C=16,F=32. FFT 256x256, half-spectrum w in [0,129).
// rowFFT -> colFFT -> pointwise einsum -> col iFFT (crop y) -> Hermitian row iFFT (crop x, Re).
// FFT kernels are WAVE-SYNCHRONOUS: each 256-pt FFT lives in 16 consecutive lanes of one wave
// (row r = tid>>4), all LDS traffic is row-local -> no __syncthreads anywhere.

constexpr int Bn = 16, Cc = 16, Ff = 32, Hh = 128, Ww = 128, Nn = 256, WH = 129;

#define DEVINL __device__ __forceinline__
DEVINL float2 f2(float a, float b) { return make_float2(a, b); }

// compiler-only memory fence (free) and write->read LDS fence (waits own writes)
#define CFENCE()   asm volatile("" ::: "memory")
#define LDSFENCE() asm volatile("s_waitcnt lgkmcnt(0)" ::: "memory")

// ---- in-register 16-point FFT, SGN=-1 forward, SGN=+1 inverse (unnormalized) ----
template<int SGN>
DEVINL void fft16r(float2 v[16]) {
  float2 t;
#define SW(a,b) { t = v[a]; v[a] = v[b]; v[b] = t; }
  SW(1, 8) SW(2, 4) SW(3, 12) SW(5, 10) SW(7, 14) SW(11, 13)
#undef SW
  const float C1 = 0.92387953251128674f, C2 = 0.70710678118654752f, C3 = 0.38268343236508977f;
  const float Ct[8] = {1.f, C1, C2, C3, 0.f, -C3, -C2, -C1};
  const float St[8] = {0.f, C3, C2, C1, 1.f, C1, C2, C3};
#pragma unroll
  for (int len = 2; len <= 16; len <<= 1) {
    const int half = len >> 1, ts = 16 / len;
#pragma unroll
    for (int i = 0; i < 16; i += len) {
#pragma unroll
      for (int j = 0; j < half; ++j) {
        const float wr = Ct[j * ts];
        const float wi = (SGN > 0) ? St[j * ts] : -St[j * ts];
        float2 b = v[i + j + half];
        float2 tt = f2(wr * b.x - wi * b.y, wr * b.y + wi * b.x);
        float2 a = v[i + j];
        v[i + j]        = f2(a.x + tt.x, a.y + tt.y);
        v[i + j + half] = f2(a.x - tt.x, a.y - tt.y);
      }
    }
  }
}

// ---- wave-synchronous 256-pt FFT: 16 lanes (t=0..15) per FFT, row-local LDS (256 float2).
// entry: v[n1] = data[t + 16*n1]; exit: v[k2] = X[t + 16*k2]. No block barriers.
template<int SGN>
DEVINL void fft256w(float2 v[16], float2* __restrict__ row, int t) {
  fft16r<SGN>(v);
  // twiddle chain: w_k = exp(SGN * 2pi i * t * k / 256)
  float sb, cb;
  __sincosf((SGN > 0 ? 0.024543692606170259f : -0.024543692606170259f) * (float)t, &sb, &cb);
  float wr = cb, wi = sb;
#pragma unroll
  for (int k = 1; k < 16; ++k) {
    float2 a = v[k];
    v[k] = f2(a.x * wr - a.y * wi, a.x * wi + a.y * wr);
    float nr = wr * cb - wi * sb, ni = wr * sb + wi * cb;
    wr = nr; wi = ni;
  }
  CFENCE();
#pragma unroll
  for (int k = 0; k < 16; ++k) row[t * 16 + ((k + t) & 15)] = v[k];   // rotated -> 4-way max
  LDSFENCE();
#pragma unroll
  for (int n2 = 0; n2 < 16; ++n2) v[n2] = row[n2 * 16 + ((t + n2) & 15)];
  CFENCE();
  fft16r<SGN>(v);
}

// ---- K1: per (b,y): 16 row FFTs over x (zero-pad 128->256), keep w in [0,129) ----
// R layout: [b][w][y][c]
__global__ __launch_bounds__(256, 5) void k1_rowfft(const float* __restrict__ img, float2* __restrict__ R) {
  __shared__ float2 lds[16 * 256];
  const int tid = threadIdx.x, r = tid >> 4, t = tid & 15;
  const int y = blockIdx.x, b = blockIdx.y;
  const float* ip = img + ((size_t)(b * Hh + y) * Ww) * Cc + r;
  float2 v[16];
#pragma unroll
  for (int j = 0; j < 8; ++j) v[j] = f2(ip[(size_t)(t + 16 * j) * Cc], 0.f);
#pragma unroll
  for (int j = 8; j < 16; ++j) v[j] = f2(0.f, 0.f);
  fft256w<-1>(v, lds + r * 256, t);
  float2* rp = R + (size_t)b * WH * Hh * Cc + (size_t)y * Cc + r;
#pragma unroll
  for (int k2 = 0; k2 < 8; ++k2) { int w = t + 16 * k2; rp[(size_t)w * Hh * Cc] = v[k2]; }
  if (t == 0) rp[(size_t)128 * Hh * Cc] = v[8];
}

// ---- K2: per (b,w): 16 column FFTs over y (zero-pad 128->256) ----
// Fimg layout: [h][w][b][c]
__global__ __launch_bounds__(256, 5) void k2_colfft(const float2* __restrict__ R, float2* __restrict__ Fimg) {
  __shared__ float2 lds[16 * 256];
  const int tid = threadIdx.x, r = tid >> 4, t = tid & 15;
  const int w = blockIdx.x, b = blockIdx.y;
  const float2* rp = R + ((size_t)(b * WH + w) * Hh) * Cc + r;
  float2 v[16];
#pragma unroll
  for (int j = 0; j < 8; ++j) v[j] = rp[(size_t)(t + 16 * j) * Cc];
#pragma unroll
  for (int j = 8; j < 16; ++j) v[j] = f2(0.f, 0.f);
  fft256w<-1>(v, lds + r * 256, t);
  float2* fp = Fimg + (size_t)w * 256 + b * 16 + r;
#pragma unroll
  for (int k2 = 0; k2 < 16; ++k2) { int h = t + 16 * k2; fp[(size_t)h * WH * 256] = v[k2]; }
}

// ---- K3: per (h,w): out_f[b,f] = sum_c Fimg[b,c] * (Kr[f,c] + i Ki[f,c]) ----
// 8 h-points per block, LDS double-buffered with register prefetch. OF layout: [w][h][b][f]
constexpr int GP = 8;
__global__ __launch_bounds__(256) void k3_mul(const float2* __restrict__ Fimg, const float* __restrict__ Kr,
                                              const float* __restrict__ Ki, float2* __restrict__ OF) {
  __shared__ float2 A[2][256];
  __shared__ float kr[2][16][33];
  __shared__ float ki[2][16][33];
  const int tid = threadIdx.x;
  const int w = blockIdx.x, h0 = blockIdx.y * GP;
  const int b0 = tid >> 5;
  const int f0 = tid & 31;
  const int cS = tid & 15, fS = tid >> 4;

  float2 aReg;
  float krA, krB, kiA, kiB;

  auto load_regs = [&](int g) {
    const size_t base = (size_t)(h0 + g) * WH + w;
    aReg = Fimg[base * 256 + tid];
    const size_t ko = base * 512;
    krA = Kr[ko + tid]; krB = Kr[ko + tid + 256];
    kiA = Ki[ko + tid]; kiB = Ki[ko + tid + 256];
  };
  auto write_lds = [&](int bb) {
    A[bb][tid] = aReg;
    kr[bb][cS][fS] = krA;  kr[bb][cS][fS + 16] = krB;
    ki[bb][cS][fS] = kiA;  ki[bb][cS][fS + 16] = kiB;
  };

  load_regs(0);
  write_lds(0);
#pragma unroll
  for (int g = 0; g < GP; ++g) {
    const int cur = g & 1;
    if (g + 1 < GP) load_regs(g + 1);
    __syncthreads();
    float2 acc0 = f2(0.f, 0.f), acc1 = f2(0.f, 0.f);
#pragma unroll
    for (int c = 0; c < 16; ++c) {
      const float krv = kr[cur][c][f0], kiv = ki[cur][c][f0];
      const float2 a0 = A[cur][b0 * 16 + c];
      const float2 a1 = A[cur][(b0 + 8) * 16 + c];
      acc0.x += a0.x * krv - a0.y * kiv;  acc0.y += a0.x * kiv + a0.y * krv;
      acc1.x += a1.x * krv - a1.y * kiv;  acc1.y += a1.x * kiv + a1.y * krv;
    }
    float2* op = OF + ((size_t)w * 256 + (h0 + g)) * 512;
    op[tid] = acc0;
    op[tid + 256] = acc1;
    if (g + 1 < GP) write_lds(cur ^ 1);
  }
}

// ---- K4: per (b,w,fg): 16 inverse column FFTs over h; store only y' = h-63 in [0,128) ----
// T layout: [b][y'][w][f]
__global__ __launch_bounds__(256, 5) void k4_colifft(const float2* __restrict__ OF, float2* __restrict__ T) {
  __shared__ float2 lds[16 * 256];
  const int tid = threadIdx.x, r = tid >> 4, t = tid & 15;
  const int w = blockIdx.x, b = blockIdx.y, fg = blockIdx.z;
  const float2* ofp = OF + (size_t)w * 256 * 512 + b * 32 + fg * 16 + r;
  float2 v[16];
#pragma unroll
  for (int j = 0; j < 16; ++j) v[j] = ofp[(size_t)(t + 16 * j) * 512];
  fft256w<1>(v, lds + r * 256, t);
  float2* tp = T + (size_t)(b * Hh) * WH * Ff + (size_t)w * Ff + fg * 16 + r;
#pragma unroll
  for (int k2 = 3; k2 < 12; ++k2) {          // compile-time reg indices; window predicate
    int h = t + 16 * k2;
    if (h >= 63 && h < 191) tp[(size_t)(h - 63) * WH * Ff] = v[k2];
  }
}

// ---- K5: per (b,y',fg): Hermitian-extend w-spectrum, inverse FFT, Re, scale, +bias, crop x ----
__global__ __launch_bounds__(256, 5) void k5_rowifft(const float2* __restrict__ T, const float* __restrict__ bias,
                                                     float* __restrict__ out) {
  __shared__ float2 lds[16 * 256];
  const int tid = threadIdx.x, r = tid >> 4, t = tid & 15;
  const int yp = blockIdx.x, b = blockIdx.y, fg = blockIdx.z;
  const float2* tp = T + ((size_t)(b * Hh + yp) * WH) * Ff + fg * 16 + r;
  float2* row = lds + r * 256;
  // stage cols 0..128 (row-local)
#pragma unroll
  for (int j = 0; j < 8; ++j) row[t + 16 * j] = tp[(size_t)(t + 16 * j) * Ff];
  if (t == 0) row[128] = tp[(size_t)128 * Ff];
  LDSFENCE();
  float2 v[16];
#pragma unroll
  for (int n1 = 0; n1 < 16; ++n1) {
    const int c = t + 16 * n1;
    if (c <= 128) v[n1] = row[c];
    else { float2 z = row[256 - c]; v[n1] = f2(z.x, -z.y); }   // Hermitian mirror
  }
  CFENCE();
  fft256w<1>(v, row, t);
  const float sc = 1.f / 65536.f;
  const float bv = bias[fg * 16 + r];
  float* op = out + ((size_t)(b * Hh + yp) * Ww) * Ff + fg * 16 + r;
#pragma unroll
  for (int k2 = 3; k2 < 12; ++k2) {
    int x = t + 16 * k2;
    if (x >= 63 && x < 191) op[(size_t)(x - 63) * Ff] = v[k2].x * sc + bv;
  }
}

extern "C" void kernel_launch(void* const* d_in, const int* in_sizes, int n_in,
                              void* d_out, int out_size, void* d_ws, size_t ws_size,
                              hipStream_t stream) {
  const float* img  = (const float*)d_in[0];
  const float* kr   = (const float*)d_in[1];
  const float* ki   = (const float*)d_in[2];
  const float* bias = (const float*)d_in[3];
  float* out = (float*)d_out;

  char* ws = (char*)d_ws;
  // region layout (lifetime-overlapped):
  //   [0, 67.6MB):     Fimg (K2->K3), later T (K4->K5)
  //   [67.6MB, 203MB): OF (K3->K4);  R (K1->K2) aliases its head (dead before K3)
  const size_t szF = (size_t)Nn * WH * Bn * Cc * sizeof(float2);   // 67,633,152
  float2* Fimg = (float2*)ws;
  float2* T    = (float2*)ws;
  float2* OF   = (float2*)(ws + szF);
  float2* R    = (float2*)(ws + szF);

  k1_rowfft <<<dim3(Hh, Bn),      256, 0, stream>>>(img, R);
  k2_colfft <<<dim3(WH, Bn),      256, 0, stream>>>(R, Fimg);
  k3_mul    <<<dim3(WH, Nn / GP), 256, 0, stream>>>(Fimg, kr, ki, OF);
  k4_colifft<<<dim3(WH, Bn, 2),   256, 0, stream>>>(OF, T);
  k5_rowifft<<<dim3(Hh, Bn, 2),   256, 0, stream>>>(T, bias, out);
}